// Round 10
// baseline (227.343 us; speedup 1.0000x reference)
//
#include <hip/hip_runtime.h>
#include <math.h>
#include <stdint.h>

#define D_MODEL 2048
#define NEXP    64
#define TOKENS  32768
#define BM      64
#define BK      64
#define NT      256
#define NCHUNK  (D_MODEL / BK)   // 32

typedef __attribute__((address_space(3))) uint32_t       lds_u32_t;
typedef const __attribute__((address_space(1))) uint32_t gbl_u32_t;

#define WAITVM(N) asm volatile("s_waitcnt vmcnt(" #N ")" ::: "memory")

__device__ __forceinline__ float sum4(float4 v) { return (v.x + v.y) + (v.z + v.w); }

// ---------- probe A: contiguous VGPR-load stream of x (m13 pattern) ----------
// 2048 blocks x 256 thr; per wave a contiguous 32KB slab, 1KB per instruction,
// 8 loads in flight; ~32 waves/CU. Measures this buffer's VGPR-path read BW.
__global__ __launch_bounds__(256) void probe_vgpr(const float* __restrict__ x,
                                                  float* __restrict__ ws)
{
    const int tid = threadIdx.x, lane = tid & 63, wave = tid >> 6;
    const float4* p = (const float4*)x + (size_t)blockIdx.x * 8192 + wave * 2048 + lane;
    float s = 0.f;
#pragma unroll 1
    for (int i = 0; i < 32; i += 8) {
        const float4 a0 = p[(size_t)(i + 0) * 64];
        const float4 a1 = p[(size_t)(i + 1) * 64];
        const float4 a2 = p[(size_t)(i + 2) * 64];
        const float4 a3 = p[(size_t)(i + 3) * 64];
        const float4 a4 = p[(size_t)(i + 4) * 64];
        const float4 a5 = p[(size_t)(i + 5) * 64];
        const float4 a6 = p[(size_t)(i + 6) * 64];
        const float4 a7 = p[(size_t)(i + 7) * 64];
        s += ((sum4(a0) + sum4(a1)) + (sum4(a2) + sum4(a3))) +
             ((sum4(a4) + sum4(a5)) + (sum4(a6) + sum4(a7)));
    }
    asm volatile("" :: "v"(s));                    // keep-alive (rule #17)
    if (lane == 0) ws[blockIdx.x * 4 + wave] = s;  // 32KB into scratch
}

// ---------- probe B: contiguous global_load_lds stream of x ----------
// 2048 blocks x 64 thr; per block a contiguous 128KB slab, 1KB packets,
// 31 packets in flight per wave, no barriers, no consumers.
__global__ __launch_bounds__(64) void probe_dma(const float* __restrict__ x)
{
    __shared__ char buf[16384];
    const int lane = threadIdx.x;
    const gbl_u32_t* src =
        (gbl_u32_t*)((const char*)x + (size_t)blockIdx.x * 131072 + lane * 16);
#pragma unroll 1
    for (int i = 0; i < 128; ++i) {
        __builtin_amdgcn_global_load_lds(src + (size_t)i * 256,
                                         (lds_u32_t*)(buf + (i & 15) * 1024), 16, 0, 0);
        WAITVM(30);                                // hold ~31 packets in flight
    }
    asm volatile("s_waitcnt vmcnt(0)" ::: "memory");
}

// ---------- main kernel: r2 verbatim (best known, 153us) ----------
#define STAGE2(c, b)                                                           \
    _Pragma("unroll")                                                          \
    for (int g = 0; g < 4; ++g) {                                              \
        const int G_ = 4 * wave + g;                                           \
        __builtin_amdgcn_global_load_lds((gbl_u32_t*)(xsrc[g] + (c) * BK),     \
                                         (lds_u32_t*)&xs[b][4 * G_][0], 16, 0, 0); \
        __builtin_amdgcn_global_load_lds((gbl_u32_t*)(wsrc[g] + (c) * BK),     \
                                         (lds_u32_t*)&ws[b][4 * G_][0], 16, 0, 0); \
    }

__global__ __launch_bounds__(NT, 2)
void router_kernel(const float* __restrict__ x, const float* __restrict__ W,
                   float* __restrict__ out)
{
    __shared__ float xs[2][BM][BK];
    __shared__ float ws[2][NEXP][BK];

    const int tid  = threadIdx.x;
    const int lane = tid & 63;
    const int wave = tid >> 6;
    const int row0 = blockIdx.x * BM;

    const int ec = tid & 15;
    const int tr = tid >> 4;

    const int lrow  = lane >> 4;
    const int lslot = lane & 15;
    const float* xsrc[4];
    const float* wsrc[4];
#pragma unroll
    for (int g = 0; g < 4; ++g) {
        const int r   = 16 * wave + 4 * g + lrow;
        const int col = 4 * (lslot ^ (r & 7));
        xsrc[g] = x + (size_t)(row0 + r) * D_MODEL + col;
        wsrc[g] = W + (size_t)r * D_MODEL + col;
    }

    float acc[4][4];
#pragma unroll
    for (int i = 0; i < 4; ++i)
#pragma unroll
        for (int j = 0; j < 4; ++j) acc[i][j] = 0.f;

    STAGE2(0, 0);
    __syncthreads();

    const int trs = tr & 7;
    const int ecs = ec & 7;

    for (int c = 0; c < NCHUNK; ++c) {
        const int buf = c & 1;
        if (c + 1 < NCHUNK) { STAGE2(c + 1, buf ^ 1); }
#pragma unroll
        for (int q = 0; q < BK / 4; ++q) {
            const int sA = 4 * (q ^ trs);
            const int sB = 4 * (q ^ ecs);
            float4 a[4], b[4];
#pragma unroll
            for (int i = 0; i < 4; ++i)
                a[i] = *(const float4*)&xs[buf][tr + 16 * i][sA];
#pragma unroll
            for (int j = 0; j < 4; ++j)
                b[j] = *(const float4*)&ws[buf][ec + 16 * j][sB];
#pragma unroll
            for (int i = 0; i < 4; ++i)
#pragma unroll
                for (int j = 0; j < 4; ++j) {
                    acc[i][j] = fmaf(a[i].x, b[j].x, acc[i][j]);
                    acc[i][j] = fmaf(a[i].y, b[j].y, acc[i][j]);
                    acc[i][j] = fmaf(a[i].z, b[j].z, acc[i][j]);
                    acc[i][j] = fmaf(a[i].w, b[j].w, acc[i][j]);
                }
        }
        __syncthreads();
    }

    float* logits = &xs[0][0][0];
#pragma unroll
    for (int i = 0; i < 4; ++i)
#pragma unroll
        for (int j = 0; j < 4; ++j)
            logits[(ec + 16 * j) * BM + (tr + 16 * i)] = acc[i][j];
    __syncthreads();

    if (tid < BM) {
        const int t = tid;
        float m1 = -INFINITY, m2 = -INFINITY;
        int i1 = 0, i2 = 0;
#pragma unroll 8
        for (int e = 0; e < NEXP; ++e) {
            float v = logits[e * BM + t];
            if (v > m1)      { m2 = m1; i2 = i1; m1 = v; i1 = e; }  // strict >: lowest index wins ties
            else if (v > m2) { m2 = v; i2 = e; }
        }
        float ex = expf(m2 - m1);
        float g1 = 1.0f / (1.0f + ex);
        float g2 = ex * g1;
        const int row = row0 + t;
        out[(size_t)row * 2 + 0] = g1;
        out[(size_t)row * 2 + 1] = g2;
        out[(size_t)TOKENS * 2 + (size_t)row * 2 + 0] = (float)i1;
        out[(size_t)TOKENS * 2 + (size_t)row * 2 + 1] = (float)i2;
    }
}

extern "C" void kernel_launch(void* const* d_in, const int* in_sizes, int n_in,
                              void* d_out, int out_size, void* d_ws, size_t ws_size,
                              hipStream_t stream) {
    const float* x = (const float*)d_in[0];
    const float* W = (const float*)d_in[1];
    float* out = (float*)d_out;
    // diagnostic probes (write only to scratch; output unaffected)
    probe_vgpr<<<2048, 256, 0, stream>>>(x, (float*)d_ws);
    probe_dma<<<2048, 64, 0, stream>>>(x);
    // main kernel: r2 verbatim
    router_kernel<<<TOKENS / BM, NT, 0, stream>>>(x, W, out);
}